// Round 1
// baseline (433.083 us; speedup 1.0000x reference)
//
#include <hip/hip_runtime.h>

typedef unsigned short ushort_t;
typedef unsigned int uint_t;
typedef __attribute__((ext_vector_type(8))) short short8;
typedef __attribute__((ext_vector_type(4))) float f32x4;

#define DIM 2048
#define BATCH 8192

// ---------- bf16 helpers (RNE) ----------
__device__ __forceinline__ ushort_t f2bf(float f) {
  union { float f; uint_t u; } x; x.f = f;
  uint_t r = x.u + 0x7fffu + ((x.u >> 16) & 1u);
  return (ushort_t)(r >> 16);
}
__device__ __forceinline__ float bf2f(ushort_t h) {
  union { uint_t u; float f; } x; x.u = ((uint_t)h) << 16; return x.f;
}

// ---------- async global->LDS 16B ----------
__device__ __forceinline__ void gload_lds16(const void* g, void* l) {
  typedef __attribute__((address_space(1))) const unsigned int gu32;
  typedef __attribute__((address_space(3))) unsigned int lu32;
  __builtin_amdgcn_global_load_lds((gu32*)g, (lu32*)l, 16, 0, 0);
}

// ---------- block reduce (256 threads) ----------
__device__ __forceinline__ float block_reduce_sum(float v) {
  #pragma unroll
  for (int off = 32; off; off >>= 1) v += __shfl_down(v, off);
  __shared__ float red[4];
  int t = threadIdx.x;
  if ((t & 63) == 0) red[t >> 6] = v;
  __syncthreads();
  return red[0] + red[1] + red[2] + red[3];
}

// ---------- c = irfft(gate, 2048)  (halfcomplex semantics: im of bin 0/1024 ignored) ----------
__global__ void k_c(const float* __restrict__ fg, float* __restrict__ c) {
  int n = blockIdx.x;          // 2048 blocks
  int t = threadIdx.x;         // 256 threads
  float s = 0.f;
  for (int k = 1 + t; k < 1024; k += 256) {
    int r = (k * n) & 2047;                     // exact phase reduction
    float sn, cs;
    sincospif((float)r * (1.0f / 1024.0f), &sn, &cs);
    s += fg[2 * k] * cs - fg[2 * k + 1] * sn;
  }
  float tot = block_reduce_sum(s);
  if (t == 0) {
    float v = fg[0] + ((n & 1) ? -fg[2048] : fg[2048]) + 2.f * tot;
    c[n] = v * (1.0f / 2048.0f);
  }
}

// ---------- b1[n] = sum_m b_in[m] * c[(n-m) mod 2048] ----------
__global__ void k_b1(const float* __restrict__ b_in, const float* __restrict__ c,
                     float* __restrict__ b1) {
  int n = blockIdx.x;
  int t = threadIdx.x;
  float s = 0.f;
  for (int m = t; m < 2048; m += 256) s += b_in[m] * c[(n - m) & 2047];
  float tot = block_reduce_sum(s);
  if (t == 0) b1[n] = tot;
}

// ---------- GT[r][col] = c[(r-col) mod 2048], bf16, packed 2/thread ----------
__global__ void k_gt(const float* __restrict__ c, uint_t* __restrict__ gt) {
  int idx = blockIdx.x * 256 + threadIdx.x;     // 2048*1024
  int r = idx >> 10;
  int c2 = (idx & 1023) << 1;
  uint_t v0 = f2bf(c[(r - c2) & 2047]);
  uint_t v1 = f2bf(c[(r - c2 - 1) & 2047]);
  gt[idx] = v0 | (v1 << 16);
}

// ---------- fp32 -> bf16 cast, 4/thread ----------
__global__ void k_cast4(const float* __restrict__ in, ushort_t* __restrict__ out) {
  long i = (long)blockIdx.x * 256 + threadIdx.x;
  float4 v = ((const float4*)in)[i];
  ushort4 o;
  o.x = f2bf(v.x); o.y = f2bf(v.y); o.z = f2bf(v.z); o.w = f2bf(v.w);
  ((ushort4*)out)[i] = o;
}

// ---------- transpose + cast: out[c][r] = bf16(in[r][c]), in is RxC ----------
__global__ void k_tc(const float* __restrict__ in, ushort_t* __restrict__ out,
                     int R, int C) {
  __shared__ float tile[32][33];
  int bc = blockIdx.x * 32;
  int br = blockIdx.y * 32;
  int tx = threadIdx.x, ty = threadIdx.y;
  #pragma unroll
  for (int i = ty; i < 32; i += 8)
    tile[i][tx] = in[(size_t)(br + i) * C + bc + tx];
  __syncthreads();
  #pragma unroll
  for (int i = ty; i < 32; i += 8)
    out[(size_t)(bc + i) * R + br + tx] = f2bf(tile[tx][i]);
}

// ---------- Wfc1eT[j][m] = bf16(W_fc1[m][j] + W_fc1[m+2048][j]) ----------
__global__ void k_fc1fold(const float* __restrict__ w, ushort_t* __restrict__ out) {
  int idx = blockIdx.x * 256 + threadIdx.x;     // 128*2048
  int j = idx >> 11;
  int m = idx & 2047;
  out[idx] = f2bf(w[(size_t)m * 128 + j] + w[(size_t)(m + 2048) * 128 + j]);
}

// ---------- MFMA GEMM: C[M][N] = A[M][K] @ B, with B given as BT[N][K] ----------
// 128x128 tile, 4 waves (2x2 of 64x64), BK=32, 16x16x32 bf16 MFMA.
// LDS XOR-swizzle: content (row,kc) stored at slot = kc ^ ((row>>1)&3); staging
// pre-swizzles the GLOBAL source so global_load_lds' linear dest works (m173).
// EPI: 0 plain bf16, 1 +bias bf16, 2 relu bf16, 3 sigmoid*aux bf16, 4 +bias f32
template <int EPI>
__launch_bounds__(256, 2)
__global__ void gemm_bt(const ushort_t* __restrict__ A, const ushort_t* __restrict__ BT,
                        void* __restrict__ C, const float* __restrict__ bias,
                        const ushort_t* __restrict__ aux, int M, int N, int K) {
  __shared__ ushort_t ldsA[128 * 32];
  __shared__ ushort_t ldsB[128 * 32];
  const int t = threadIdx.x;
  const int wave = t >> 6, lane = t & 63;
  const int bm = blockIdx.x, bn = blockIdx.y;
  const int wr = wave >> 1, wc = wave & 1;
  const int lrow = lane & 15, lk = lane >> 4;

  f32x4 acc[4][4] = {};

  const size_t arow0 = (size_t)bm * 128;
  const size_t brow0 = (size_t)bn * 128;

  for (int k0 = 0; k0 < K; k0 += 32) {
    if (k0) __syncthreads();
    #pragma unroll
    for (int h = 0; h < 2; ++h) {
      int q = t + h * 256;                 // chunk 0..511
      int row = q >> 2, slot = q & 3;
      int kc = slot ^ ((row >> 1) & 3);    // pre-swizzled source chunk
      const ushort_t* ga = A + (arow0 + row) * K + k0 + kc * 8;
      gload_lds16(ga, &ldsA[(wave * 64 + h * 256) * 8]);
      const ushort_t* gb = BT + (brow0 + row) * K + k0 + kc * 8;
      gload_lds16(gb, &ldsB[(wave * 64 + h * 256) * 8]);
    }
    __syncthreads();

    short8 af[4], bfr[4];
    #pragma unroll
    for (int m = 0; m < 4; ++m) {
      int row = wr * 64 + m * 16 + lrow;
      int slot = lk ^ ((row >> 1) & 3);
      af[m] = *(const short8*)&ldsA[row * 32 + slot * 8];
      int rowb = wc * 64 + m * 16 + lrow;
      int slotb = lk ^ ((rowb >> 1) & 3);
      bfr[m] = *(const short8*)&ldsB[rowb * 32 + slotb * 8];
    }
    #pragma unroll
    for (int m = 0; m < 4; ++m)
      #pragma unroll
      for (int n = 0; n < 4; ++n)
        acc[m][n] = __builtin_amdgcn_mfma_f32_16x16x32_bf16(af[m], bfr[n], acc[m][n], 0, 0, 0);
  }

  const int rbase = bm * 128 + wr * 64;
  const int cbase = bn * 128 + wc * 64;
  #pragma unroll
  for (int m = 0; m < 4; ++m) {
    #pragma unroll
    for (int n = 0; n < 4; ++n) {
      int col = cbase + n * 16 + lrow;
      int row0 = rbase + m * 16 + lk * 4;
      #pragma unroll
      for (int j = 0; j < 4; ++j) {
        int r = row0 + j;
        float v = acc[m][n][j];
        size_t off = (size_t)r * N + col;
        if constexpr (EPI == 0) {
          ((ushort_t*)C)[off] = f2bf(v);
        } else if constexpr (EPI == 1) {
          ((ushort_t*)C)[off] = f2bf(v + bias[col]);
        } else if constexpr (EPI == 2) {
          ((ushort_t*)C)[off] = f2bf(v > 0.f ? v : 0.f);
        } else if constexpr (EPI == 3) {
          float y = 1.f / (1.f + __expf(-v));
          ((ushort_t*)C)[off] = f2bf(bf2f(aux[off]) * y);
        } else {
          ((float*)C)[off] = v + bias[col];
        }
      }
    }
  }
}

extern "C" void kernel_launch(void* const* d_in, const int* in_sizes, int n_in,
                              void* d_out, int out_size, void* d_ws, size_t ws_size,
                              hipStream_t stream) {
  const float* x     = (const float*)d_in[0];
  const float* W_in  = (const float*)d_in[1];
  const float* b_in  = (const float*)d_in[2];
  const float* W_out = (const float*)d_in[3];
  const float* b_out = (const float*)d_in[4];
  const float* fg    = (const float*)d_in[5];
  const float* W_fc1 = (const float*)d_in[6];
  const float* W_fc2 = (const float*)d_in[7];

  char* ws = (char*)d_ws;
  float*    c_buf  = (float*)(ws + 0);               // 8 KB
  float*    b1     = (float*)(ws + 8192);            // 8 KB
  ushort_t* WinBf  = (ushort_t*)(ws + 16384);        // 8 MB
  ushort_t* W1T    = (ushort_t*)(ws + 8404992);      // 8 MB
  ushort_t* WoutT  = (ushort_t*)(ws + 16793600);     // 8 MB
  ushort_t* Wfc1eT = (ushort_t*)(ws + 25182208);     // 512 KB
  ushort_t* Wfc2T  = (ushort_t*)(ws + 25706496);     // 512 KB
  ushort_t* x_bf   = (ushort_t*)(ws + 26230784);     // 32 MB
  ushort_t* ht_bf  = (ushort_t*)(ws + 59785216);     // 32 MB
  ushort_t* a_bf   = (ushort_t*)(ws + 93339648);     // 2 MB
  ushort_t* GT     = (ushort_t*)(ws + 95436800);     // 8 MB (dead after fold GEMM)
  ushort_t* g_bf   = (ushort_t*)(ws + 95436800);     // 32 MB, aliases GT safely
  // total ws use: 128,991,232 bytes (~123 MB)
  (void)ws_size; (void)in_sizes; (void)n_in; (void)out_size;

  // prep
  k_c<<<2048, 256, 0, stream>>>(fg, c_buf);
  k_b1<<<2048, 256, 0, stream>>>(b_in, c_buf, b1);
  k_gt<<<8192, 256, 0, stream>>>(c_buf, (uint_t*)GT);
  k_cast4<<<16384, 256, 0, stream>>>(x, x_bf);               // 8192x2048
  k_cast4<<<4096, 256, 0, stream>>>(W_in, WinBf);            // 2048x2048
  k_tc<<<dim3(64, 64), dim3(32, 8), 0, stream>>>(W_out, WoutT, 2048, 2048);
  k_tc<<<dim3(64, 4), dim3(32, 8), 0, stream>>>(W_fc2, Wfc2T, 128, 2048);
  k_fc1fold<<<1024, 256, 0, stream>>>(W_fc1, Wfc1eT);

  // W1T = GT @ (WinBf as BT)   [2048 x 2048]
  gemm_bt<0><<<dim3(16, 16), 256, 0, stream>>>(GT, WinBf, W1T, nullptr, nullptr,
                                               2048, 2048, 2048);
  // ht = x @ W1 + b1           [8192 x 2048] bf16
  gemm_bt<1><<<dim3(64, 16), 256, 0, stream>>>(x_bf, W1T, ht_bf, b1, nullptr,
                                               8192, 2048, 2048);
  // a = relu(ht @ Wfc1e)       [8192 x 128] bf16
  gemm_bt<2><<<dim3(64, 1), 256, 0, stream>>>(ht_bf, Wfc1eT, a_bf, nullptr, nullptr,
                                              8192, 128, 2048);
  // g = ht * sigmoid(a @ Wfc2) [8192 x 2048] bf16
  gemm_bt<3><<<dim3(64, 16), 256, 0, stream>>>(a_bf, Wfc2T, g_bf, nullptr, ht_bf,
                                               8192, 2048, 128);
  // out = g @ W_out + b_out    [8192 x 2048] f32
  gemm_bt<4><<<dim3(64, 16), 256, 0, stream>>>(g_bf, WoutT, (float*)d_out, b_out, nullptr,
                                               8192, 2048, 2048);
}

// Round 2
// 422.097 us; speedup vs baseline: 1.0260x; 1.0260x over previous
//
#include <hip/hip_runtime.h>

typedef unsigned short ushort_t;
typedef unsigned int uint_t;
typedef __attribute__((ext_vector_type(8))) short short8;
typedef __attribute__((ext_vector_type(4))) float f32x4;

#define DIM 2048
#define BATCH 8192

// ---------- bf16 helpers (RNE) ----------
__device__ __forceinline__ ushort_t f2bf(float f) {
  union { float f; uint_t u; } x; x.f = f;
  uint_t r = x.u + 0x7fffu + ((x.u >> 16) & 1u);
  return (ushort_t)(r >> 16);
}
__device__ __forceinline__ float bf2f(ushort_t h) {
  union { uint_t u; float f; } x; x.u = ((uint_t)h) << 16; return x.f;
}

// ---------- async global->LDS 16B ----------
__device__ __forceinline__ void gload_lds16(const void* g, void* l) {
  typedef __attribute__((address_space(1))) const unsigned int gu32;
  typedef __attribute__((address_space(3))) unsigned int lu32;
  __builtin_amdgcn_global_load_lds((gu32*)g, (lu32*)l, 16, 0, 0);
}

// ---------- block reduce (256 threads) ----------
__device__ __forceinline__ float block_reduce_sum(float v) {
  #pragma unroll
  for (int off = 32; off; off >>= 1) v += __shfl_down(v, off);
  __shared__ float red[4];
  int t = threadIdx.x;
  if ((t & 63) == 0) red[t >> 6] = v;
  __syncthreads();
  return red[0] + red[1] + red[2] + red[3];
}

// ---------- c = irfft(gate, 2048) ----------
__global__ void k_c(const float* __restrict__ fg, float* __restrict__ c) {
  int n = blockIdx.x;
  int t = threadIdx.x;
  float s = 0.f;
  for (int k = 1 + t; k < 1024; k += 256) {
    int r = (k * n) & 2047;
    float sn, cs;
    sincospif((float)r * (1.0f / 1024.0f), &sn, &cs);
    s += fg[2 * k] * cs - fg[2 * k + 1] * sn;
  }
  float tot = block_reduce_sum(s);
  if (t == 0) {
    float v = fg[0] + ((n & 1) ? -fg[2048] : fg[2048]) + 2.f * tot;
    c[n] = v * (1.0f / 2048.0f);
  }
}

// ---------- b1[n] = sum_m b_in[m] * c[(n-m) mod 2048] ----------
__global__ void k_b1(const float* __restrict__ b_in, const float* __restrict__ c,
                     float* __restrict__ b1) {
  int n = blockIdx.x;
  int t = threadIdx.x;
  float s = 0.f;
  for (int m = t; m < 2048; m += 256) s += b_in[m] * c[(n - m) & 2047];
  float tot = block_reduce_sum(s);
  if (t == 0) b1[n] = tot;
}

// ---------- GT[r][col] = c[(r-col) mod 2048], bf16 ----------
__global__ void k_gt(const float* __restrict__ c, uint_t* __restrict__ gt) {
  int idx = blockIdx.x * 256 + threadIdx.x;
  int r = idx >> 10;
  int c2 = (idx & 1023) << 1;
  uint_t v0 = f2bf(c[(r - c2) & 2047]);
  uint_t v1 = f2bf(c[(r - c2 - 1) & 2047]);
  gt[idx] = v0 | (v1 << 16);
}

// ---------- fp32 -> bf16 cast, 4/thread ----------
__global__ void k_cast4(const float* __restrict__ in, ushort_t* __restrict__ out) {
  long i = (long)blockIdx.x * 256 + threadIdx.x;
  float4 v = ((const float4*)in)[i];
  ushort4 o;
  o.x = f2bf(v.x); o.y = f2bf(v.y); o.z = f2bf(v.z); o.w = f2bf(v.w);
  ((ushort4*)out)[i] = o;
}

// ---------- transpose + cast ----------
__global__ void k_tc(const float* __restrict__ in, ushort_t* __restrict__ out,
                     int R, int C) {
  __shared__ float tile[32][33];
  int bc = blockIdx.x * 32;
  int br = blockIdx.y * 32;
  int tx = threadIdx.x, ty = threadIdx.y;
  #pragma unroll
  for (int i = ty; i < 32; i += 8)
    tile[i][tx] = in[(size_t)(br + i) * C + bc + tx];
  __syncthreads();
  #pragma unroll
  for (int i = ty; i < 32; i += 8)
    out[(size_t)(bc + i) * R + br + tx] = f2bf(tile[tx][i]);
}

// ---------- Wfc1eT[j][m] = bf16(W_fc1[m][j] + W_fc1[m+2048][j]) ----------
__global__ void k_fc1fold(const float* __restrict__ w, ushort_t* __restrict__ out) {
  int idx = blockIdx.x * 256 + threadIdx.x;
  int j = idx >> 11;
  int m = idx & 2047;
  out[idx] = f2bf(w[(size_t)m * 128 + j] + w[(size_t)(m + 2048) * 128 + j]);
}

// ---------- reduce 4 split-K partials + relu + cast ----------
__global__ void k_red4relu(const float* __restrict__ p, ushort_t* __restrict__ out) {
  int i = blockIdx.x * 256 + threadIdx.x;       // 8192*128 = 1048576
  float s = p[i] + p[i + 1048576] + p[i + 2097152] + p[i + 3145728];
  out[i] = f2bf(s > 0.f ? s : 0.f);
}

// ================= 128^2 MFMA GEMM (m97 structure) =================
// EPI: 0 plain bf16, 1 +bias bf16, 2 relu bf16, 3 sigmoid*aux bf16, 4 +bias f32,
//      5 split-K f32 partial (grid.z = 4 slices)
template <int EPI>
__launch_bounds__(256, 2)
__global__ void gemm_bt(const ushort_t* __restrict__ A, const ushort_t* __restrict__ BT,
                        void* __restrict__ C, const float* __restrict__ bias,
                        const ushort_t* __restrict__ aux, int M, int N, int K) {
  __shared__ ushort_t ldsA[128 * 32];
  __shared__ ushort_t ldsB[128 * 32];
  const int t = threadIdx.x;
  const int wave = t >> 6, lane = t & 63;
  const int bm = blockIdx.x, bn = blockIdx.y;
  const int wr = wave >> 1, wc = wave & 1;
  const int lrow = lane & 15, lk = lane >> 4;

  f32x4 acc[4][4] = {};

  const size_t arow0 = (size_t)bm * 128;
  const size_t brow0 = (size_t)bn * 128;

  int kb = 0, ke = K;
  if constexpr (EPI == 5) { int ks = K >> 2; kb = blockIdx.z * ks; ke = kb + ks; }

  for (int k0 = kb; k0 < ke; k0 += 32) {
    if (k0 != kb) __syncthreads();
    #pragma unroll
    for (int h = 0; h < 2; ++h) {
      int q = t + h * 256;
      int row = q >> 2, slot = q & 3;
      int kc = slot ^ ((row >> 1) & 3);
      const ushort_t* ga = A + (arow0 + row) * K + k0 + kc * 8;
      gload_lds16(ga, &ldsA[(wave * 64 + h * 256) * 8]);
      const ushort_t* gb = BT + (brow0 + row) * K + k0 + kc * 8;
      gload_lds16(gb, &ldsB[(wave * 64 + h * 256) * 8]);
    }
    __syncthreads();

    short8 af[4], bfr[4];
    #pragma unroll
    for (int m = 0; m < 4; ++m) {
      int row = wr * 64 + m * 16 + lrow;
      int slot = lk ^ ((row >> 1) & 3);
      af[m] = *(const short8*)&ldsA[row * 32 + slot * 8];
      int rowb = wc * 64 + m * 16 + lrow;
      int slotb = lk ^ ((rowb >> 1) & 3);
      bfr[m] = *(const short8*)&ldsB[rowb * 32 + slotb * 8];
    }
    #pragma unroll
    for (int m = 0; m < 4; ++m)
      #pragma unroll
      for (int n = 0; n < 4; ++n)
        acc[m][n] = __builtin_amdgcn_mfma_f32_16x16x32_bf16(af[m], bfr[n], acc[m][n], 0, 0, 0);
  }

  const int rbase = bm * 128 + wr * 64;
  const int cbase = bn * 128 + wc * 64;
  #pragma unroll
  for (int m = 0; m < 4; ++m) {
    #pragma unroll
    for (int n = 0; n < 4; ++n) {
      int col = cbase + n * 16 + lrow;
      int row0 = rbase + m * 16 + lk * 4;
      #pragma unroll
      for (int j = 0; j < 4; ++j) {
        int r = row0 + j;
        float v = acc[m][n][j];
        size_t off = (size_t)r * N + col;
        if constexpr (EPI == 0) {
          ((ushort_t*)C)[off] = f2bf(v);
        } else if constexpr (EPI == 1) {
          ((ushort_t*)C)[off] = f2bf(v + bias[col]);
        } else if constexpr (EPI == 2) {
          ((ushort_t*)C)[off] = f2bf(v > 0.f ? v : 0.f);
        } else if constexpr (EPI == 3) {
          float y = 1.f / (1.f + __expf(-v));
          ((ushort_t*)C)[off] = f2bf(bf2f(aux[off]) * y);
        } else if constexpr (EPI == 4) {
          ((float*)C)[off] = v + bias[col];
        } else {
          ((float*)C)[off + (size_t)blockIdx.z * ((size_t)M * N)] = v;
        }
      }
    }
  }
}

// ================= 256^2 8-phase MFMA GEMM (m201 structure) =================
// BM=BN=256, BK=64, 512 thr = 8 waves (2M x 4N), per-wave 128x64 out.
// LDS 128KB: buf b at b*65536; A halves at +0/+16384; B halves at +32768/+49152.
// st_16x32 swizzle: byte ^= ((byte>>9)&1)<<5; staging pre-swizzles the GLOBAL
// source (linear gload_lds dest), reads apply the same XOR. Counted vmcnt(4)
// at phases 3 and 7 only; raw s_barrier (never __syncthreads) in the loop.
__device__ __forceinline__ void stage_half(const ushort_t* __restrict__ src, size_t gr0,
                                           int k0b, int ksb, char* ldsHalf, int t) {
  #pragma unroll
  for (int l = 0; l < 2; ++l) {
    int o = (l * 512 + t) * 16;
    int s = o ^ (((o >> 9) & 1) << 5);
    int row = s >> 7, cbyte = s & 127;
    const char* g = (const char*)src + (gr0 + row) * (size_t)ksb + k0b + cbyte;
    char* dst = ldsHalf + (l * 512 + (t & ~63)) * 16;   // wave-uniform base
    gload_lds16(g, dst);
  }
}

__device__ __forceinline__ short8 ldfrag(const char* regionBase, int R, int kk, int lk) {
  int r = R & 127, h = R >> 7;
  int lin = r * 128 + kk * 64 + lk * 16;
  int sw = lin ^ (((lin >> 9) & 1) << 5);
  return *(const short8*)(regionBase + h * 16384 + sw);
}

template <int EPI>   // 1: +bias bf16 out; 4: +bias f32 out
__launch_bounds__(512, 2)
__global__ void gemm256(const ushort_t* __restrict__ A, const ushort_t* __restrict__ BT,
                        void* __restrict__ C, const float* __restrict__ bias,
                        int N, int K, int nbn) {
  __shared__ __align__(16) char L[131072];
  const int t = threadIdx.x;
  const int lane = t & 63, wave = t >> 6;
  const int wm = wave >> 2, wn = wave & 3;
  const int lrow = lane & 15, lk = lane >> 4;

  // bijective XCD swizzle (gridDim.x % 8 == 0)
  int d = blockIdx.x;
  int cpx = gridDim.x >> 3;
  int wg = (d & 7) * cpx + (d >> 3);
  const int bm = wg / nbn, bn = wg % nbn;

  const size_t am0 = (size_t)bm * 256;
  const size_t bn0 = (size_t)bn * 256;
  const int ksb = K * 2;
  const int NT = K >> 6;            // K-tiles; K % 128 == 0 so NT even

  f32x4 acc[8][4] = {};

  // prologue: tile0 (A+B) -> buf0, tile1 B -> buf1  (12 loads/thread-pair, 6 half-tiles)
  stage_half(A,  am0,       0,   ksb, L + 0,             t);
  stage_half(A,  am0 + 128, 0,   ksb, L + 16384,         t);
  stage_half(BT, bn0,       0,   ksb, L + 32768,         t);
  stage_half(BT, bn0 + 128, 0,   ksb, L + 49152,         t);
  stage_half(BT, bn0,       128, ksb, L + 65536 + 32768, t);
  stage_half(BT, bn0 + 128, 128, ksb, L + 65536 + 49152, t);
  asm volatile("s_waitcnt vmcnt(4)" ::: "memory");   // tile0 complete; B(1) in flight
  __builtin_amdgcn_s_barrier();

  short8 bfrag[4][2];
  short8 afrag[2][2];

  for (int T = 0; T < NT; T += 2) {
    int k1 = ((T + 1 < NT) ? T + 1 : NT - 1) * 128;
    int k2 = ((T + 2 < NT) ? T + 2 : NT - 1) * 128;
    int k3 = ((T + 3 < NT) ? T + 3 : NT - 1) * 128;
    #pragma unroll
    for (int ph = 0; ph < 8; ++ph) {
      const int cb = ph >> 2;          // compute buffer
      const int cp = ph & 3;           // phase within K-tile
      const char* Ab = L + cb * 65536;
      const char* Bb = L + cb * 65536 + 32768;
      if (cp == 0) {
        #pragma unroll
        for (int n = 0; n < 4; ++n)
          #pragma unroll
          for (int kk = 0; kk < 2; ++kk)
            bfrag[n][kk] = ldfrag(Bb, wn * 64 + n * 16 + lrow, kk, lk);
      }
      #pragma unroll
      for (int mi = 0; mi < 2; ++mi)
        #pragma unroll
        for (int kk = 0; kk < 2; ++kk)
          afrag[mi][kk] = ldfrag(Ab, wm * 128 + (cp * 2 + mi) * 16 + lrow, kk, lk);

      // staging schedule: each region provably dead before restage;
      // vmcnt(4) covers everything needed >= 1 phase before its first read.
      if (ph == 0) {
        stage_half(A, am0,       k1, ksb, L + 65536,         t);
        stage_half(A, am0 + 128, k1, ksb, L + 65536 + 16384, t);
      } else if (ph == 1) {
        stage_half(BT, bn0,       k2, ksb, L + 32768, t);
      } else if (ph == 2) {
        stage_half(BT, bn0 + 128, k2, ksb, L + 49152, t);
      } else if (ph == 3) {
        asm volatile("s_waitcnt vmcnt(4)" ::: "memory");  // A(T+1),B(T+1) ready
      } else if (ph == 4) {
        stage_half(A, am0,       k2, ksb, L + 0,     t);
      } else if (ph == 5) {
        stage_half(A, am0 + 128, k2, ksb, L + 16384, t);
      } else if (ph == 6) {
        stage_half(BT, bn0,       k3, ksb, L + 65536 + 32768, t);
      } else {
        stage_half(BT, bn0 + 128, k3, ksb, L + 65536 + 49152, t);
        asm volatile("s_waitcnt vmcnt(4)" ::: "memory");  // A(T+2),B(T+2) ready
      }

      __builtin_amdgcn_s_barrier();
      asm volatile("s_waitcnt lgkmcnt(0)" ::: "memory");
      __builtin_amdgcn_sched_barrier(0);
      __builtin_amdgcn_s_setprio(1);
      #pragma unroll
      for (int mi = 0; mi < 2; ++mi)
        #pragma unroll
        for (int n = 0; n < 4; ++n)
          #pragma unroll
          for (int kk = 0; kk < 2; ++kk)
            acc[cp * 2 + mi][n] = __builtin_amdgcn_mfma_f32_16x16x32_bf16(
                afrag[mi][kk], bfrag[n][kk], acc[cp * 2 + mi][n], 0, 0, 0);
      __builtin_amdgcn_s_setprio(0);
      __builtin_amdgcn_s_barrier();
    }
  }

  const int rbase = bm * 256 + wm * 128;
  const int cbase = bn * 256 + wn * 64;
  #pragma unroll
  for (int mi = 0; mi < 8; ++mi) {
    #pragma unroll
    for (int n = 0; n < 4; ++n) {
      int col = cbase + n * 16 + lrow;
      int row0 = rbase + mi * 16 + lk * 4;
      float bcol = bias[col];
      #pragma unroll
      for (int j = 0; j < 4; ++j) {
        float v = acc[mi][n][j] + bcol;
        size_t off = (size_t)(row0 + j) * N + col;
        if constexpr (EPI == 1) ((ushort_t*)C)[off] = f2bf(v);
        else                    ((float*)C)[off] = v;
      }
    }
  }
}

extern "C" void kernel_launch(void* const* d_in, const int* in_sizes, int n_in,
                              void* d_out, int out_size, void* d_ws, size_t ws_size,
                              hipStream_t stream) {
  const float* x     = (const float*)d_in[0];
  const float* W_in  = (const float*)d_in[1];
  const float* b_in  = (const float*)d_in[2];
  const float* W_out = (const float*)d_in[3];
  const float* b_out = (const float*)d_in[4];
  const float* fg    = (const float*)d_in[5];
  const float* W_fc1 = (const float*)d_in[6];
  const float* W_fc2 = (const float*)d_in[7];

  char* ws = (char*)d_ws;
  float*    c_buf  = (float*)(ws + 0);               // 8 KB
  float*    b1     = (float*)(ws + 8192);            // 8 KB
  ushort_t* WinBf  = (ushort_t*)(ws + 16384);        // 8 MB
  ushort_t* W1T    = (ushort_t*)(ws + 8404992);      // 8 MB
  ushort_t* WoutT  = (ushort_t*)(ws + 16793600);     // 8 MB
  ushort_t* Wfc1eT = (ushort_t*)(ws + 25182208);     // 512 KB
  ushort_t* Wfc2T  = (ushort_t*)(ws + 25706496);     // 512 KB
  ushort_t* x_bf   = (ushort_t*)(ws + 26230784);     // 32 MB (dead after ht GEMM)
  float*    fcp    = (float*)(ws + 26230784);        // 16 MB, aliases x_bf
  ushort_t* ht_bf  = (ushort_t*)(ws + 59785216);     // 32 MB
  ushort_t* a_bf   = (ushort_t*)(ws + 93339648);     // 2 MB
  ushort_t* GT     = (ushort_t*)(ws + 95436800);     // 8 MB (dead after fold GEMM)
  ushort_t* g_bf   = (ushort_t*)(ws + 95436800);     // 32 MB, aliases GT
  (void)ws_size; (void)in_sizes; (void)n_in; (void)out_size;

  // prep
  k_c<<<2048, 256, 0, stream>>>(fg, c_buf);
  k_b1<<<2048, 256, 0, stream>>>(b_in, c_buf, b1);
  k_gt<<<8192, 256, 0, stream>>>(c_buf, (uint_t*)GT);
  k_cast4<<<16384, 256, 0, stream>>>(x, x_bf);
  k_cast4<<<4096, 256, 0, stream>>>(W_in, WinBf);
  k_tc<<<dim3(64, 64), dim3(32, 8), 0, stream>>>(W_out, WoutT, 2048, 2048);
  k_tc<<<dim3(64, 4), dim3(32, 8), 0, stream>>>(W_fc2, Wfc2T, 128, 2048);
  k_fc1fold<<<1024, 256, 0, stream>>>(W_fc1, Wfc1eT);

  // W1T = GT @ WinBf^T   [2048 x 2048]
  gemm_bt<0><<<dim3(16, 16), 256, 0, stream>>>(GT, WinBf, W1T, nullptr, nullptr,
                                               2048, 2048, 2048);
  // ht = x @ W1 + b1     [8192 x 2048] bf16   (256^2 8-phase)
  gemm256<1><<<256, 512, 0, stream>>>(x_bf, W1T, ht_bf, b1, 2048, 2048, 8);
  // fc1 split-K x4: partials = ht @ Wfc1e    [4][8192 x 128] f32
  gemm_bt<5><<<dim3(64, 1, 4), 256, 0, stream>>>(ht_bf, Wfc1eT, fcp, nullptr, nullptr,
                                                 8192, 128, 2048);
  // a = relu(sum partials)                    [8192 x 128] bf16
  k_red4relu<<<4096, 256, 0, stream>>>(fcp, a_bf);
  // g = ht * sigmoid(a @ Wfc2)               [8192 x 2048] bf16
  gemm_bt<3><<<dim3(64, 16), 256, 0, stream>>>(a_bf, Wfc2T, g_bf, nullptr, ht_bf,
                                               8192, 2048, 128);
  // out = g @ W_out + b_out                  [8192 x 2048] f32  (256^2 8-phase)
  gemm256<4><<<256, 512, 0, stream>>>(g_bf, WoutT, (float*)d_out, b_out, 2048, 2048, 8);
}

// Round 4
// 376.952 us; speedup vs baseline: 1.1489x; 1.1198x over previous
//
#include <hip/hip_runtime.h>

typedef unsigned short ushort_t;
typedef unsigned int uint_t;
typedef __attribute__((ext_vector_type(8))) short short8;
typedef __attribute__((ext_vector_type(4))) float f32x4;

#define DIM 2048
#define BATCH 8192

// ---------- bf16 helpers (RNE) ----------
__device__ __forceinline__ ushort_t f2bf(float f) {
  union { float f; uint_t u; } x; x.f = f;
  uint_t r = x.u + 0x7fffu + ((x.u >> 16) & 1u);
  return (ushort_t)(r >> 16);
}
__device__ __forceinline__ float bf2f(ushort_t h) {
  union { uint_t u; float f; } x; x.u = ((uint_t)h) << 16; return x.f;
}

// ---------- async global->LDS 16B ----------
__device__ __forceinline__ void gload_lds16(const void* g, void* l) {
  typedef __attribute__((address_space(1))) const unsigned int gu32;
  typedef __attribute__((address_space(3))) unsigned int lu32;
  __builtin_amdgcn_global_load_lds((gu32*)g, (lu32*)l, 16, 0, 0);
}

// ---------- block reduce (256 threads) ----------
__device__ __forceinline__ float block_reduce_sum(float v) {
  #pragma unroll
  for (int off = 32; off; off >>= 1) v += __shfl_down(v, off);
  __shared__ float red[4];
  int t = threadIdx.x;
  if ((t & 63) == 0) red[t >> 6] = v;
  __syncthreads();
  return red[0] + red[1] + red[2] + red[3];
}

// ---------- c = irfft(gate, 2048) ----------
__global__ void k_c(const float* __restrict__ fg, float* __restrict__ c) {
  int n = blockIdx.x;
  int t = threadIdx.x;
  float s = 0.f;
  for (int k = 1 + t; k < 1024; k += 256) {
    int r = (k * n) & 2047;
    float sn, cs;
    sincospif((float)r * (1.0f / 1024.0f), &sn, &cs);
    s += fg[2 * k] * cs - fg[2 * k + 1] * sn;
  }
  float tot = block_reduce_sum(s);
  if (t == 0) {
    float v = fg[0] + ((n & 1) ? -fg[2048] : fg[2048]) + 2.f * tot;
    c[n] = v * (1.0f / 2048.0f);
  }
}

// ---------- b1[n] = sum_m b_in[m] * c[(n-m) mod 2048] ----------
__global__ void k_b1(const float* __restrict__ b_in, const float* __restrict__ c,
                     float* __restrict__ b1) {
  int n = blockIdx.x;
  int t = threadIdx.x;
  float s = 0.f;
  for (int m = t; m < 2048; m += 256) s += b_in[m] * c[(n - m) & 2047];
  float tot = block_reduce_sum(s);
  if (t == 0) b1[n] = tot;
}

// ---------- GT[r][col] = c[(r-col) mod 2048], bf16 ----------
__global__ void k_gt(const float* __restrict__ c, uint_t* __restrict__ gt) {
  int idx = blockIdx.x * 256 + threadIdx.x;
  int r = idx >> 10;
  int c2 = (idx & 1023) << 1;
  uint_t v0 = f2bf(c[(r - c2) & 2047]);
  uint_t v1 = f2bf(c[(r - c2 - 1) & 2047]);
  gt[idx] = v0 | (v1 << 16);
}

// ---------- fp32 -> bf16 cast, 4/thread ----------
__global__ void k_cast4(const float* __restrict__ in, ushort_t* __restrict__ out) {
  long i = (long)blockIdx.x * 256 + threadIdx.x;
  float4 v = ((const float4*)in)[i];
  ushort4 o;
  o.x = f2bf(v.x); o.y = f2bf(v.y); o.z = f2bf(v.z); o.w = f2bf(v.w);
  ((ushort4*)out)[i] = o;
}

// ---------- transpose + cast ----------
__global__ void k_tc(const float* __restrict__ in, ushort_t* __restrict__ out,
                     int R, int C) {
  __shared__ float tile[32][33];
  int bc = blockIdx.x * 32;
  int br = blockIdx.y * 32;
  int tx = threadIdx.x, ty = threadIdx.y;
  #pragma unroll
  for (int i = ty; i < 32; i += 8)
    tile[i][tx] = in[(size_t)(br + i) * C + bc + tx];
  __syncthreads();
  #pragma unroll
  for (int i = ty; i < 32; i += 8)
    out[(size_t)(bc + i) * R + br + tx] = f2bf(tile[tx][i]);
}

// ---------- Wfc1eT[j][m] = bf16(W_fc1[m][j] + W_fc1[m+2048][j]) ----------
__global__ void k_fc1fold(const float* __restrict__ w, ushort_t* __restrict__ out) {
  int idx = blockIdx.x * 256 + threadIdx.x;
  int j = idx >> 11;
  int m = idx & 2047;
  out[idx] = f2bf(w[(size_t)m * 128 + j] + w[(size_t)(m + 2048) * 128 + j]);
}

// ---------- reduce 4 split-K partials + relu + cast ----------
__global__ void k_red4relu(const float* __restrict__ p, ushort_t* __restrict__ out) {
  int i = blockIdx.x * 256 + threadIdx.x;       // 8192*128 = 1048576
  float s = p[i] + p[i + 1048576] + p[i + 2097152] + p[i + 3145728];
  out[i] = f2bf(s > 0.f ? s : 0.f);
}

// ================= 128^2 MFMA GEMM (m97 structure) =================
// EPI: 0 plain bf16, 1 +bias bf16, 2 relu bf16, 3 sigmoid*aux bf16, 4 +bias f32,
//      5 split-K f32 partial (grid.z = 4 slices)
template <int EPI>
__launch_bounds__(256, 2)
__global__ void gemm_bt(const ushort_t* __restrict__ A, const ushort_t* __restrict__ BT,
                        void* __restrict__ C, const float* __restrict__ bias,
                        const ushort_t* __restrict__ aux, int M, int N, int K) {
  __shared__ ushort_t ldsA[128 * 32];
  __shared__ ushort_t ldsB[128 * 32];
  const int t = threadIdx.x;
  const int wave = t >> 6, lane = t & 63;
  const int bm = blockIdx.x, bn = blockIdx.y;
  const int wr = wave >> 1, wc = wave & 1;
  const int lrow = lane & 15, lk = lane >> 4;

  f32x4 acc[4][4] = {};

  const size_t arow0 = (size_t)bm * 128;
  const size_t brow0 = (size_t)bn * 128;

  int kb = 0, ke = K;
  if constexpr (EPI == 5) { int ks = K >> 2; kb = blockIdx.z * ks; ke = kb + ks; }

  for (int k0 = kb; k0 < ke; k0 += 32) {
    if (k0 != kb) __syncthreads();
    #pragma unroll
    for (int h = 0; h < 2; ++h) {
      int q = t + h * 256;
      int row = q >> 2, slot = q & 3;
      int kc = slot ^ ((row >> 1) & 3);
      const ushort_t* ga = A + (arow0 + row) * K + k0 + kc * 8;
      gload_lds16(ga, &ldsA[(wave * 64 + h * 256) * 8]);
      const ushort_t* gb = BT + (brow0 + row) * K + k0 + kc * 8;
      gload_lds16(gb, &ldsB[(wave * 64 + h * 256) * 8]);
    }
    __syncthreads();

    short8 af[4], bfr[4];
    #pragma unroll
    for (int m = 0; m < 4; ++m) {
      int row = wr * 64 + m * 16 + lrow;
      int slot = lk ^ ((row >> 1) & 3);
      af[m] = *(const short8*)&ldsA[row * 32 + slot * 8];
      int rowb = wc * 64 + m * 16 + lrow;
      int slotb = lk ^ ((rowb >> 1) & 3);
      bfr[m] = *(const short8*)&ldsB[rowb * 32 + slotb * 8];
    }
    #pragma unroll
    for (int m = 0; m < 4; ++m)
      #pragma unroll
      for (int n = 0; n < 4; ++n)
        acc[m][n] = __builtin_amdgcn_mfma_f32_16x16x32_bf16(af[m], bfr[n], acc[m][n], 0, 0, 0);
  }

  const int rbase = bm * 128 + wr * 64;
  const int cbase = bn * 128 + wc * 64;
  #pragma unroll
  for (int m = 0; m < 4; ++m) {
    #pragma unroll
    for (int n = 0; n < 4; ++n) {
      int col = cbase + n * 16 + lrow;
      int row0 = rbase + m * 16 + lk * 4;
      #pragma unroll
      for (int j = 0; j < 4; ++j) {
        int r = row0 + j;
        float v = acc[m][n][j];
        size_t off = (size_t)r * N + col;
        if constexpr (EPI == 0) {
          ((ushort_t*)C)[off] = f2bf(v);
        } else if constexpr (EPI == 1) {
          ((ushort_t*)C)[off] = f2bf(v + bias[col]);
        } else if constexpr (EPI == 2) {
          ((ushort_t*)C)[off] = f2bf(v > 0.f ? v : 0.f);
        } else if constexpr (EPI == 3) {
          float y = 1.f / (1.f + __expf(-v));
          ((ushort_t*)C)[off] = f2bf(bf2f(aux[off]) * y);
        } else if constexpr (EPI == 4) {
          ((float*)C)[off] = v + bias[col];
        } else {
          ((float*)C)[off + (size_t)blockIdx.z * ((size_t)M * N)] = v;
        }
      }
    }
  }
}

// ================= 256^2 8-phase MFMA GEMM (m201 structure) =================
// BM=BN=256, BK=64, 512 thr = 8 waves (2M x 4N), per-wave 128x64 out.
// LDS 128KB: buf b at b*65536; A halves at +0/+16384; B halves at +32768/+49152.
// Each half: 128 rows x 128 bytes. Swizzle (G4, 128B rows): within-row column
// chunk XORed with (row&7)<<4 — bijective involution on bits 4..6; spreads the
// 16 rows of each lk-group across all 8 chunks (2 lanes/chunk = free, m136).
// Staging keeps gload_lds' LINEAR dest and pre-applies the same involution to
// the GLOBAL source column (rule #21). Counted vmcnt(4) at phases 3 and 7 only;
// raw s_barrier (never __syncthreads) in the loop.
__device__ __forceinline__ void stage_half(const ushort_t* __restrict__ src, size_t gr0,
                                           int k0b, int ksb, char* ldsHalf, int t) {
  #pragma unroll
  for (int l = 0; l < 2; ++l) {
    int p = (l * 512 + t) * 16;                 // physical byte offset in half
    int row = p >> 7;
    int cb = (p & 127) ^ ((row & 7) << 4);      // content column byte (involution)
    const char* g = (const char*)src + (gr0 + row) * (size_t)ksb + k0b + cb;
    char* dst = ldsHalf + (l * 512 + (t & ~63)) * 16;   // wave-uniform base
    gload_lds16(g, dst);
  }
}

__device__ __forceinline__ short8 ldfrag(const char* regionBase, int R, int kk, int lk) {
  int r = R & 127, h = R >> 7;
  int col = (kk * 64 + lk * 16) ^ ((r & 7) << 4);
  return *(const short8*)(regionBase + h * 16384 + r * 128 + col);
}

template <int EPI>   // 1: +bias bf16 out; 4: +bias f32 out
__launch_bounds__(512, 2)
__global__ void gemm256(const ushort_t* __restrict__ A, const ushort_t* __restrict__ BT,
                        void* __restrict__ C, const float* __restrict__ bias,
                        int N, int K, int nbn) {
  __shared__ __align__(16) char L[131072];
  const int t = threadIdx.x;
  const int lane = t & 63, wave = t >> 6;
  const int wm = wave >> 2, wn = wave & 3;
  const int lrow = lane & 15, lk = lane >> 4;

  // bijective XCD swizzle (gridDim.x % 8 == 0)
  int d = blockIdx.x;
  int cpx = gridDim.x >> 3;
  int wg = (d & 7) * cpx + (d >> 3);
  const int bm = wg / nbn, bn = wg % nbn;

  const size_t am0 = (size_t)bm * 256;
  const size_t bn0 = (size_t)bn * 256;
  const int ksb = K * 2;
  const int NT = K >> 6;            // K-tiles; K % 128 == 0 so NT even

  f32x4 acc[8][4] = {};

  // prologue: tile0 (A+B) -> buf0, tile1 B -> buf1
  stage_half(A,  am0,       0,   ksb, L + 0,             t);
  stage_half(A,  am0 + 128, 0,   ksb, L + 16384,         t);
  stage_half(BT, bn0,       0,   ksb, L + 32768,         t);
  stage_half(BT, bn0 + 128, 0,   ksb, L + 49152,         t);
  stage_half(BT, bn0,       128, ksb, L + 65536 + 32768, t);
  stage_half(BT, bn0 + 128, 128, ksb, L + 65536 + 49152, t);
  asm volatile("s_waitcnt vmcnt(4)" ::: "memory");   // tile0 complete; B(1) in flight
  __builtin_amdgcn_s_barrier();

  short8 bfrag[4][2];
  short8 afrag[2][2];

  for (int T = 0; T < NT; T += 2) {
    int k1 = ((T + 1 < NT) ? T + 1 : NT - 1) * 128;
    int k2 = ((T + 2 < NT) ? T + 2 : NT - 1) * 128;
    int k3 = ((T + 3 < NT) ? T + 3 : NT - 1) * 128;
    #pragma unroll
    for (int ph = 0; ph < 8; ++ph) {
      const int cb = ph >> 2;          // compute buffer
      const int cp = ph & 3;           // phase within K-tile
      const char* Ab = L + cb * 65536;
      const char* Bb = L + cb * 65536 + 32768;
      if (cp == 0) {
        #pragma unroll
        for (int n = 0; n < 4; ++n)
          #pragma unroll
          for (int kk = 0; kk < 2; ++kk)
            bfrag[n][kk] = ldfrag(Bb, wn * 64 + n * 16 + lrow, kk, lk);
      }
      #pragma unroll
      for (int mi = 0; mi < 2; ++mi)
        #pragma unroll
        for (int kk = 0; kk < 2; ++kk)
          afrag[mi][kk] = ldfrag(Ab, wm * 128 + (cp * 2 + mi) * 16 + lrow, kk, lk);

      // staging schedule: each region provably dead before restage;
      // vmcnt(4) covers everything needed >= 1 phase before its first read.
      if (ph == 0) {
        stage_half(A, am0,       k1, ksb, L + 65536,         t);
        stage_half(A, am0 + 128, k1, ksb, L + 65536 + 16384, t);
      } else if (ph == 1) {
        stage_half(BT, bn0,       k2, ksb, L + 32768, t);
      } else if (ph == 2) {
        stage_half(BT, bn0 + 128, k2, ksb, L + 49152, t);
      } else if (ph == 3) {
        asm volatile("s_waitcnt vmcnt(4)" ::: "memory");  // A(T+1),B(T+1) ready
      } else if (ph == 4) {
        stage_half(A, am0,       k2, ksb, L + 0,     t);
      } else if (ph == 5) {
        stage_half(A, am0 + 128, k2, ksb, L + 16384, t);
      } else if (ph == 6) {
        stage_half(BT, bn0,       k3, ksb, L + 65536 + 32768, t);
      } else {
        stage_half(BT, bn0 + 128, k3, ksb, L + 65536 + 49152, t);
        asm volatile("s_waitcnt vmcnt(4)" ::: "memory");  // A(T+2),B(T+2) ready
      }

      __builtin_amdgcn_s_barrier();
      asm volatile("s_waitcnt lgkmcnt(0)" ::: "memory");
      __builtin_amdgcn_sched_barrier(0);
      __builtin_amdgcn_s_setprio(1);
      #pragma unroll
      for (int mi = 0; mi < 2; ++mi)
        #pragma unroll
        for (int n = 0; n < 4; ++n)
          #pragma unroll
          for (int kk = 0; kk < 2; ++kk)
            acc[cp * 2 + mi][n] = __builtin_amdgcn_mfma_f32_16x16x32_bf16(
                afrag[mi][kk], bfrag[n][kk], acc[cp * 2 + mi][n], 0, 0, 0);
      __builtin_amdgcn_s_setprio(0);
      __builtin_amdgcn_s_barrier();
    }
  }

  const int rbase = bm * 256 + wm * 128;
  const int cbase = bn * 256 + wn * 64;
  #pragma unroll
  for (int mi = 0; mi < 8; ++mi) {
    #pragma unroll
    for (int n = 0; n < 4; ++n) {
      int col = cbase + n * 16 + lrow;
      int row0 = rbase + mi * 16 + lk * 4;
      float bcol = bias[col];
      #pragma unroll
      for (int j = 0; j < 4; ++j) {
        float v = acc[mi][n][j] + bcol;
        size_t off = (size_t)(row0 + j) * N + col;
        if constexpr (EPI == 1) ((ushort_t*)C)[off] = f2bf(v);
        else                    ((float*)C)[off] = v;
      }
    }
  }
}

extern "C" void kernel_launch(void* const* d_in, const int* in_sizes, int n_in,
                              void* d_out, int out_size, void* d_ws, size_t ws_size,
                              hipStream_t stream) {
  const float* x     = (const float*)d_in[0];
  const float* W_in  = (const float*)d_in[1];
  const float* b_in  = (const float*)d_in[2];
  const float* W_out = (const float*)d_in[3];
  const float* b_out = (const float*)d_in[4];
  const float* fg    = (const float*)d_in[5];
  const float* W_fc1 = (const float*)d_in[6];
  const float* W_fc2 = (const float*)d_in[7];

  char* ws = (char*)d_ws;
  float*    c_buf  = (float*)(ws + 0);               // 8 KB
  float*    b1     = (float*)(ws + 8192);            // 8 KB
  ushort_t* WinBf  = (ushort_t*)(ws + 16384);        // 8 MB
  ushort_t* W1T    = (ushort_t*)(ws + 8404992);      // 8 MB
  ushort_t* WoutT  = (ushort_t*)(ws + 16793600);     // 8 MB
  ushort_t* Wfc1eT = (ushort_t*)(ws + 25182208);     // 512 KB
  ushort_t* Wfc2T  = (ushort_t*)(ws + 25706496);     // 512 KB
  ushort_t* x_bf   = (ushort_t*)(ws + 26230784);     // 32 MB (dead after ht GEMM)
  float*    fcp    = (float*)(ws + 26230784);        // 16 MB, aliases x_bf
  ushort_t* ht_bf  = (ushort_t*)(ws + 59785216);     // 32 MB
  ushort_t* a_bf   = (ushort_t*)(ws + 93339648);     // 2 MB
  ushort_t* GT     = (ushort_t*)(ws + 95436800);     // 8 MB (dead after fold GEMM)
  ushort_t* g_bf   = (ushort_t*)(ws + 95436800);     // 32 MB, aliases GT
  (void)ws_size; (void)in_sizes; (void)n_in; (void)out_size;

  // prep
  k_c<<<2048, 256, 0, stream>>>(fg, c_buf);
  k_b1<<<2048, 256, 0, stream>>>(b_in, c_buf, b1);
  k_gt<<<8192, 256, 0, stream>>>(c_buf, (uint_t*)GT);
  k_cast4<<<16384, 256, 0, stream>>>(x, x_bf);
  k_cast4<<<4096, 256, 0, stream>>>(W_in, WinBf);
  k_tc<<<dim3(64, 64), dim3(32, 8), 0, stream>>>(W_out, WoutT, 2048, 2048);
  k_tc<<<dim3(64, 4), dim3(32, 8), 0, stream>>>(W_fc2, Wfc2T, 128, 2048);
  k_fc1fold<<<1024, 256, 0, stream>>>(W_fc1, Wfc1eT);

  // W1T = GT @ WinBf^T   [2048 x 2048]
  gemm_bt<0><<<dim3(16, 16), 256, 0, stream>>>(GT, WinBf, W1T, nullptr, nullptr,
                                               2048, 2048, 2048);
  // ht = x @ W1 + b1     [8192 x 2048] bf16   (256^2 8-phase)
  gemm256<1><<<256, 512, 0, stream>>>(x_bf, W1T, ht_bf, b1, 2048, 2048, 8);
  // fc1 split-K x4: partials = ht @ Wfc1e    [4][8192 x 128] f32
  gemm_bt<5><<<dim3(64, 1, 4), 256, 0, stream>>>(ht_bf, Wfc1eT, fcp, nullptr, nullptr,
                                                 8192, 128, 2048);
  // a = relu(sum partials)                    [8192 x 128] bf16
  k_red4relu<<<4096, 256, 0, stream>>>(fcp, a_bf);
  // g = ht * sigmoid(a @ Wfc2)               [8192 x 2048] bf16
  gemm_bt<3><<<dim3(64, 16), 256, 0, stream>>>(a_bf, Wfc2T, g_bf, nullptr, ht_bf,
                                               8192, 2048, 128);
  // out = g @ W_out + b_out                  [8192 x 2048] f32  (256^2 8-phase)
  gemm256<4><<<256, 512, 0, stream>>>(g_bf, WoutT, (float*)d_out, b_out, 2048, 2048, 8);
}